// Round 7
// baseline (4904.731 us; speedup 1.0000x reference)
//
#include <hip/hip_runtime.h>
#include <hip/hip_bf16.h>

// Encoder block, M = 32*577 = 18464 rows, D=768, H=12, HD=64, HID=3072.
// GEMMs bf16 MFMA (16x16x32), fp32 accumulate. Output d_out = FLOAT32
// (reference returns f32; round-1..5 wrote bf16 -> checker read packed pairs
// as f32 -> shuffled-compare error ~10.0, attention-invariant. Fixed here.)
// Round 7: identical resubmit of round 6 (infra timeout, no signal).

#define M_ROWS 18464
#define NHEAD 12

typedef __attribute__((ext_vector_type(8))) short s16x8;
typedef __attribute__((ext_vector_type(4))) float f32x4;

__device__ __forceinline__ unsigned short f2bf(float f) {
  union { float f; unsigned u; } v; v.f = f;
  return (unsigned short)((v.u + 0x7fffu + ((v.u >> 16) & 1u)) >> 16);
}
__device__ __forceinline__ float bf2f(unsigned short h) {
  union { unsigned u; float f; } v; v.u = ((unsigned)h) << 16;
  return v.f;
}

__device__ __forceinline__ void gload_lds16(const void* g, void* l) {
  __builtin_amdgcn_global_load_lds((const __attribute__((address_space(1))) unsigned*)g,
                                   (__attribute__((address_space(3))) unsigned*)l, 16, 0, 0);
}

// ---------------- weight cast + transpose: f32 [K,N] -> bf16 [N,K] ----------------
__global__ __launch_bounds__(256) void wtrans(const float* __restrict__ in,
                                              unsigned short* __restrict__ out,
                                              int K, int N) {
  __shared__ float t[32][33];
  const int n0 = blockIdx.x * 32, k0 = blockIdx.y * 32;
  const int tx = threadIdx.x, ty = threadIdx.y;
  for (int i = ty; i < 32; i += 8)
    t[i][tx] = in[(size_t)(k0 + i) * N + n0 + tx];
  __syncthreads();
  for (int i = ty; i < 32; i += 8)
    out[(size_t)(n0 + i) * K + k0 + tx] = f2bf(t[tx][i]);
}

// ---------------- LayerNorm (1 wave per row), f32 in -> bf16 out ----------------
__global__ __launch_bounds__(256) void ln1_kernel(const float* __restrict__ x,
    const float* __restrict__ g, const float* __restrict__ be,
    unsigned short* __restrict__ out) {
  const int w = threadIdx.x >> 6, l = threadIdx.x & 63;
  const size_t row = (size_t)blockIdx.x * 4 + w;
  const float* xr = x + row * 768;
  f32x4 v[3];
#pragma unroll
  for (int s = 0; s < 3; s++) v[s] = ((const f32x4*)xr)[s * 64 + l];
  float sm = 0.f, sq = 0.f;
#pragma unroll
  for (int s = 0; s < 3; s++)
#pragma unroll
    for (int j = 0; j < 4; j++) { sm += v[s][j]; sq += v[s][j] * v[s][j]; }
#pragma unroll
  for (int o = 1; o < 64; o <<= 1) { sm += __shfl_xor(sm, o); sq += __shfl_xor(sq, o); }
  const float mean = sm * (1.f / 768.f);
  const float rs = rsqrtf(sq * (1.f / 768.f) - mean * mean + 1e-5f);
  unsigned short* orow = out + row * 768;
#pragma unroll
  for (int s = 0; s < 3; s++) {
    int col = s * 256 + l * 4;
    unsigned short h4[4];
#pragma unroll
    for (int j = 0; j < 4; j++)
      h4[j] = f2bf((v[s][j] - mean) * rs * g[col + j] + be[col + j]);
    uint2 u; u.x = h4[0] | ((unsigned)h4[1] << 16); u.y = h4[2] | ((unsigned)h4[3] << 16);
    *(uint2*)(orow + col) = u;
  }
}

// ---------------- double LayerNorm (LN(g2,be2) then LN(g3,be3)) ----------------
__global__ __launch_bounds__(256) void ln2_kernel(const float* __restrict__ xin,
    const float* __restrict__ g2, const float* __restrict__ be2,
    const float* __restrict__ g3, const float* __restrict__ be3,
    unsigned short* __restrict__ out) {
  const int w = threadIdx.x >> 6, l = threadIdx.x & 63;
  const size_t row = (size_t)blockIdx.x * 4 + w;
  const float* xr = xin + row * 768;
  f32x4 v[3];
#pragma unroll
  for (int s = 0; s < 3; s++) v[s] = ((const f32x4*)xr)[s * 64 + l];
  float sm = 0.f, sq = 0.f;
#pragma unroll
  for (int s = 0; s < 3; s++)
#pragma unroll
    for (int j = 0; j < 4; j++) { sm += v[s][j]; sq += v[s][j] * v[s][j]; }
#pragma unroll
  for (int o = 1; o < 64; o <<= 1) { sm += __shfl_xor(sm, o); sq += __shfl_xor(sq, o); }
  float mean = sm * (1.f / 768.f);
  float rs = rsqrtf(sq * (1.f / 768.f) - mean * mean + 1e-5f);
  float y[12];
  sm = 0.f; sq = 0.f;
#pragma unroll
  for (int s = 0; s < 3; s++) {
    int col = s * 256 + l * 4;
#pragma unroll
    for (int j = 0; j < 4; j++) {
      float t = (v[s][j] - mean) * rs * g2[col + j] + be2[col + j];
      y[s * 4 + j] = t; sm += t; sq += t * t;
    }
  }
#pragma unroll
  for (int o = 1; o < 64; o <<= 1) { sm += __shfl_xor(sm, o); sq += __shfl_xor(sq, o); }
  mean = sm * (1.f / 768.f);
  rs = rsqrtf(sq * (1.f / 768.f) - mean * mean + 1e-5f);
  unsigned short* orow = out + row * 768;
#pragma unroll
  for (int s = 0; s < 3; s++) {
    int col = s * 256 + l * 4;
    unsigned short h4[4];
#pragma unroll
    for (int j = 0; j < 4; j++)
      h4[j] = f2bf((y[s * 4 + j] - mean) * rs * g3[col + j] + be3[col + j]);
    uint2 u; u.x = h4[0] | ((unsigned)h4[1] << 16); u.y = h4[2] | ((unsigned)h4[3] << 16);
    *(uint2*)(orow + col) = u;
  }
}

// ---------------- NT GEMM: A[M,K] bf16 x BT[N,K] bf16 -> epilogue ----------------
// EPI: 0 = +bias -> bf16 (QKV)
//      1 = +bias + aux(f32) -> f32 (proj: res1 = x + attn@W + b)
//      2 = +bias, exact GELU -> bf16 (MLP1)
//      3 = +bias + aux(f32) -> f32 (MLP2 -> d_out, f32 per reference dtype)
template<int EPI>
__global__ __launch_bounds__(256) void gemm_nt(
    const unsigned short* __restrict__ A, const unsigned short* __restrict__ BT,
    const float* __restrict__ bias, const float* __restrict__ aux,
    void* __restrict__ Cout, int M, int N, int K) {
  __shared__ unsigned short As[128 * 32];
  __shared__ unsigned short Bs[128 * 32];
  const int tid = threadIdx.x;
  const int w = tid >> 6, l = tid & 63;
  const int m0 = blockIdx.x * 128, n0 = blockIdx.y * 128;
  const int r0 = w * 32 + (l >> 2);
  const int kof = (l & 3) * 8;
  const int lr = l & 15, lg = l >> 4;
  const int wr = (w >> 1) * 64, wc = (w & 1) * 64;
  f32x4 acc[4][4];
#pragma unroll
  for (int m = 0; m < 4; m++)
#pragma unroll
    for (int n = 0; n < 4; n++)
#pragma unroll
      for (int r = 0; r < 4; r++) acc[m][n][r] = 0.f;

  char* AsB = (char*)As; char* BsB = (char*)Bs;
  int ar0 = m0 + r0;      if (ar0 >= M) ar0 = M - 1;
  int ar1 = m0 + r0 + 16; if (ar1 >= M) ar1 = M - 1;
  const size_t a0 = (size_t)ar0 * K + kof;
  const size_t a1 = (size_t)ar1 * K + kof;
  const size_t b0 = (size_t)(n0 + r0) * K + kof;
  const size_t b1 = (size_t)(n0 + r0 + 16) * K + kof;

  for (int k0 = 0; k0 < K; k0 += 32) {
    __syncthreads();
    gload_lds16(A + a0 + k0, AsB + (w * 2 + 0) * 1024);
    gload_lds16(A + a1 + k0, AsB + (w * 2 + 1) * 1024);
    gload_lds16(BT + b0 + k0, BsB + (w * 2 + 0) * 1024);
    gload_lds16(BT + b1 + k0, BsB + (w * 2 + 1) * 1024);
    __syncthreads();
    s16x8 af[4], bf[4];
#pragma unroll
    for (int m = 0; m < 4; m++)
      af[m] = *(const s16x8*)(AsB + (wr + m * 16 + lr) * 64 + lg * 16);
#pragma unroll
    for (int n = 0; n < 4; n++)
      bf[n] = *(const s16x8*)(BsB + (wc + n * 16 + lr) * 64 + lg * 16);
#pragma unroll
    for (int m = 0; m < 4; m++)
#pragma unroll
      for (int n = 0; n < 4; n++)
        acc[m][n] = __builtin_amdgcn_mfma_f32_16x16x32_bf16(af[m], bf[n], acc[m][n], 0, 0, 0);
  }

  float bs[4];
#pragma unroll
  for (int n = 0; n < 4; n++) bs[n] = bias[n0 + wc + n * 16 + lr];
#pragma unroll
  for (int m = 0; m < 4; m++) {
#pragma unroll
    for (int r = 0; r < 4; r++) {
      int row = m0 + wr + m * 16 + lg * 4 + r;
      if (row >= M) continue;
      size_t rb = (size_t)row * N;
#pragma unroll
      for (int n = 0; n < 4; n++) {
        int col = n0 + wc + n * 16 + lr;
        float c = acc[m][n][r] + bs[n];
        if (EPI == 0) {
          ((unsigned short*)Cout)[rb + col] = f2bf(c);
        } else if (EPI == 1) {
          ((float*)Cout)[rb + col] = c + aux[rb + col];
        } else if (EPI == 2) {
          c = 0.5f * c * (1.f + erff(c * 0.70710678118f));
          ((unsigned short*)Cout)[rb + col] = f2bf(c);
        } else {
          ((float*)Cout)[rb + col] = c + aux[rb + col];   // f32 final output
        }
      }
    }
  }
}

// ---------------- simple attention: one wave per (b,h,q-row), pure VALU ----------------
// Diagnostic-grade: f32 softmax, no MFMA, no fragment-layout assumptions.
__global__ __launch_bounds__(256) void attn_simple(const unsigned short* __restrict__ qkv,
                                                   unsigned short* __restrict__ out) {
  __shared__ float Qs[4][64];
  __shared__ float Ps[4][608];
  const int w = threadIdx.x >> 6, l = threadIdx.x & 63;
  const int bh = blockIdx.x / 145, qi = blockIdx.x % 145;
  const int b = bh / NHEAD, h = bh % NHEAD;
  const int qq = qi * 4 + w;
  const int q = qq > 576 ? 576 : qq;
  const size_t rowb = (size_t)(b * 577) * 2304;
  const unsigned short* qp = qkv + rowb + (size_t)q * 2304 + h * 64;
  Qs[w][l] = bf2f(qp[l]);
  __syncthreads();

  float s[10];
#pragma unroll
  for (int jj = 0; jj < 10; jj++) {
    int j = jj * 64 + l;
    int jc = j > 576 ? 576 : j;
    const unsigned short* kp = qkv + rowb + (size_t)jc * 2304 + 768 + h * 64;
    float dot = 0.f;
#pragma unroll
    for (int d0 = 0; d0 < 64; d0 += 8) {
      s16x8 kv = *(const s16x8*)(kp + d0);
#pragma unroll
      for (int u = 0; u < 8; u++)
        dot += Qs[w][d0 + u] * bf2f((unsigned short)kv[u]);
    }
    s[jj] = (j <= 576) ? dot * 0.125f : -3e38f;
  }
  float m = s[0];
#pragma unroll
  for (int jj = 1; jj < 10; jj++) m = fmaxf(m, s[jj]);
#pragma unroll
  for (int o = 1; o < 64; o <<= 1) m = fmaxf(m, __shfl_xor(m, o));
  float sum = 0.f;
#pragma unroll
  for (int jj = 0; jj < 10; jj++) {
    int j = jj * 64 + l;
    if (j <= 576) { float p = __expf(s[jj] - m); sum += p; Ps[w][j] = p; }
  }
#pragma unroll
  for (int o = 1; o < 64; o <<= 1) sum += __shfl_xor(sum, o);
  __syncthreads();

  const unsigned short* vp = qkv + rowb + 1536 + h * 64 + l;
  float oacc = 0.f;
  for (int j = 0; j < 577; j++)
    oacc += Ps[w][j] * bf2f(vp[(size_t)j * 2304]);
  oacc /= sum;
  if (qq <= 576)
    out[(size_t)(b * 577 + qq) * 768 + h * 64 + l] = f2bf(oacc);
}

extern "C" void kernel_launch(void* const* d_in, const int* in_sizes, int n_in,
                              void* d_out, int out_size, void* d_ws, size_t ws_size,
                              hipStream_t stream) {
  const float* x      = (const float*)d_in[0];
  const float* w_qkv  = (const float*)d_in[1];
  const float* b_qkv  = (const float*)d_in[2];
  const float* w_proj = (const float*)d_in[3];
  const float* b_proj = (const float*)d_in[4];
  const float* g1  = (const float*)d_in[5];
  const float* be1 = (const float*)d_in[6];
  const float* g2  = (const float*)d_in[7];
  const float* be2 = (const float*)d_in[8];
  const float* g3  = (const float*)d_in[9];
  const float* be3 = (const float*)d_in[10];
  const float* w1  = (const float*)d_in[11];
  const float* bm1 = (const float*)d_in[12];
  const float* w2  = (const float*)d_in[13];
  const float* bm2 = (const float*)d_in[14];

  // workspace layout (bytes), total ~212.7 MB:
  //  [0,        3538944)  wqkvT   2304x768 bf16
  //  [3538944,  4718592)  wprojT   768x768 bf16
  //  [4718592,  9437184)  w1T     3072x768 bf16
  //  [9437184, 14155776)  w2T     768x3072 bf16
  //  [14155776,42516480)  hbuf    [M,768] bf16   (h1, then attnb, then h2)
  //  [42516480,155959296) qkv     [M,2304] bf16  (later hid [M,3072])
  //  [155959296,212680704) res1   [M,768] f32
  char* ws = (char*)d_ws;
  unsigned short* wqkvT  = (unsigned short*)(ws + 0);
  unsigned short* wprojT = (unsigned short*)(ws + 3538944);
  unsigned short* w1T    = (unsigned short*)(ws + 4718592);
  unsigned short* w2T    = (unsigned short*)(ws + 9437184);
  unsigned short* hbuf   = (unsigned short*)(ws + 14155776);
  unsigned short* qkv    = (unsigned short*)(ws + 42516480);
  unsigned short* hid    = qkv;
  unsigned short* attnb  = hbuf;   // alias: h1 dead after QKV GEMM
  float*          res1   = (float*)(ws + 155959296);

  dim3 b32(32, 8);
  wtrans<<<dim3(2304 / 32, 768 / 32),  b32, 0, stream>>>(w_qkv,  wqkvT,  768, 2304);
  wtrans<<<dim3(768 / 32, 768 / 32),   b32, 0, stream>>>(w_proj, wprojT, 768, 768);
  wtrans<<<dim3(3072 / 32, 768 / 32),  b32, 0, stream>>>(w1,     w1T,    768, 3072);
  wtrans<<<dim3(768 / 32, 3072 / 32),  b32, 0, stream>>>(w2,     w2T,    3072, 768);

  ln1_kernel<<<4616, 256, 0, stream>>>(x, g1, be1, hbuf);
  gemm_nt<0><<<dim3(145, 18), 256, 0, stream>>>(hbuf, wqkvT, b_qkv, nullptr, qkv, M_ROWS, 2304, 768);
  attn_simple<<<32 * NHEAD * 145, 256, 0, stream>>>(qkv, attnb);
  gemm_nt<1><<<dim3(145, 6), 256, 0, stream>>>(attnb, wprojT, b_proj, x, res1, M_ROWS, 768, 768);
  ln2_kernel<<<4616, 256, 0, stream>>>(res1, g2, be2, g3, be3, hbuf);
  gemm_nt<2><<<dim3(145, 24), 256, 0, stream>>>(hbuf, w1T, bm1, nullptr, hid, M_ROWS, 3072, 768);
  gemm_nt<3><<<dim3(145, 6), 256, 0, stream>>>(hid, w2T, bm2, res1, (float*)d_out, M_ROWS, 768, 3072);
}

// Round 8
// 875.861 us; speedup vs baseline: 5.5999x; 5.5999x over previous
//
#include <hip/hip_runtime.h>
#include <hip/hip_bf16.h>

// Encoder block, M = 32*577 = 18464 rows, D=768, H=12, HD=64, HID=3072.
// GEMMs bf16 MFMA (16x16x32), fp32 accumulate. Output d_out = FLOAT32.
// Round 8: single change vs round 7 = MFMA flash attention back in
// (round-5 proved the old error was output-dtype, not attention).

#define M_ROWS 18464
#define NHEAD 12

typedef __attribute__((ext_vector_type(8))) short s16x8;
typedef __attribute__((ext_vector_type(4))) float f32x4;

__device__ __forceinline__ unsigned short f2bf(float f) {
  union { float f; unsigned u; } v; v.f = f;
  return (unsigned short)((v.u + 0x7fffu + ((v.u >> 16) & 1u)) >> 16);
}
__device__ __forceinline__ float bf2f(unsigned short h) {
  union { unsigned u; float f; } v; v.u = ((unsigned)h) << 16;
  return v.f;
}

__device__ __forceinline__ void gload_lds16(const void* g, void* l) {
  __builtin_amdgcn_global_load_lds((const __attribute__((address_space(1))) unsigned*)g,
                                   (__attribute__((address_space(3))) unsigned*)l, 16, 0, 0);
}

// ---------------- weight cast + transpose: f32 [K,N] -> bf16 [N,K] ----------------
__global__ __launch_bounds__(256) void wtrans(const float* __restrict__ in,
                                              unsigned short* __restrict__ out,
                                              int K, int N) {
  __shared__ float t[32][33];
  const int n0 = blockIdx.x * 32, k0 = blockIdx.y * 32;
  const int tx = threadIdx.x, ty = threadIdx.y;
  for (int i = ty; i < 32; i += 8)
    t[i][tx] = in[(size_t)(k0 + i) * N + n0 + tx];
  __syncthreads();
  for (int i = ty; i < 32; i += 8)
    out[(size_t)(n0 + i) * K + k0 + tx] = f2bf(t[tx][i]);
}

// ---------------- LayerNorm (1 wave per row), f32 in -> bf16 out ----------------
__global__ __launch_bounds__(256) void ln1_kernel(const float* __restrict__ x,
    const float* __restrict__ g, const float* __restrict__ be,
    unsigned short* __restrict__ out) {
  const int w = threadIdx.x >> 6, l = threadIdx.x & 63;
  const size_t row = (size_t)blockIdx.x * 4 + w;
  const float* xr = x + row * 768;
  f32x4 v[3];
#pragma unroll
  for (int s = 0; s < 3; s++) v[s] = ((const f32x4*)xr)[s * 64 + l];
  float sm = 0.f, sq = 0.f;
#pragma unroll
  for (int s = 0; s < 3; s++)
#pragma unroll
    for (int j = 0; j < 4; j++) { sm += v[s][j]; sq += v[s][j] * v[s][j]; }
#pragma unroll
  for (int o = 1; o < 64; o <<= 1) { sm += __shfl_xor(sm, o); sq += __shfl_xor(sq, o); }
  const float mean = sm * (1.f / 768.f);
  const float rs = rsqrtf(sq * (1.f / 768.f) - mean * mean + 1e-5f);
  unsigned short* orow = out + row * 768;
#pragma unroll
  for (int s = 0; s < 3; s++) {
    int col = s * 256 + l * 4;
    unsigned short h4[4];
#pragma unroll
    for (int j = 0; j < 4; j++)
      h4[j] = f2bf((v[s][j] - mean) * rs * g[col + j] + be[col + j]);
    uint2 u; u.x = h4[0] | ((unsigned)h4[1] << 16); u.y = h4[2] | ((unsigned)h4[3] << 16);
    *(uint2*)(orow + col) = u;
  }
}

// ---------------- double LayerNorm (LN(g2,be2) then LN(g3,be3)) ----------------
__global__ __launch_bounds__(256) void ln2_kernel(const float* __restrict__ xin,
    const float* __restrict__ g2, const float* __restrict__ be2,
    const float* __restrict__ g3, const float* __restrict__ be3,
    unsigned short* __restrict__ out) {
  const int w = threadIdx.x >> 6, l = threadIdx.x & 63;
  const size_t row = (size_t)blockIdx.x * 4 + w;
  const float* xr = xin + row * 768;
  f32x4 v[3];
#pragma unroll
  for (int s = 0; s < 3; s++) v[s] = ((const f32x4*)xr)[s * 64 + l];
  float sm = 0.f, sq = 0.f;
#pragma unroll
  for (int s = 0; s < 3; s++)
#pragma unroll
    for (int j = 0; j < 4; j++) { sm += v[s][j]; sq += v[s][j] * v[s][j]; }
#pragma unroll
  for (int o = 1; o < 64; o <<= 1) { sm += __shfl_xor(sm, o); sq += __shfl_xor(sq, o); }
  float mean = sm * (1.f / 768.f);
  float rs = rsqrtf(sq * (1.f / 768.f) - mean * mean + 1e-5f);
  float y[12];
  sm = 0.f; sq = 0.f;
#pragma unroll
  for (int s = 0; s < 3; s++) {
    int col = s * 256 + l * 4;
#pragma unroll
    for (int j = 0; j < 4; j++) {
      float t = (v[s][j] - mean) * rs * g2[col + j] + be2[col + j];
      y[s * 4 + j] = t; sm += t; sq += t * t;
    }
  }
#pragma unroll
  for (int o = 1; o < 64; o <<= 1) { sm += __shfl_xor(sm, o); sq += __shfl_xor(sq, o); }
  mean = sm * (1.f / 768.f);
  rs = rsqrtf(sq * (1.f / 768.f) - mean * mean + 1e-5f);
  unsigned short* orow = out + row * 768;
#pragma unroll
  for (int s = 0; s < 3; s++) {
    int col = s * 256 + l * 4;
    unsigned short h4[4];
#pragma unroll
    for (int j = 0; j < 4; j++)
      h4[j] = f2bf((y[s * 4 + j] - mean) * rs * g3[col + j] + be3[col + j]);
    uint2 u; u.x = h4[0] | ((unsigned)h4[1] << 16); u.y = h4[2] | ((unsigned)h4[3] << 16);
    *(uint2*)(orow + col) = u;
  }
}

// ---------------- NT GEMM: A[M,K] bf16 x BT[N,K] bf16 -> epilogue ----------------
// EPI: 0 = +bias -> bf16 (QKV)
//      1 = +bias + aux(f32) -> f32 (proj: res1 = x + attn@W + b)
//      2 = +bias, exact GELU -> bf16 (MLP1)
//      3 = +bias + aux(f32) -> f32 (MLP2 -> d_out, f32 per reference dtype)
template<int EPI>
__global__ __launch_bounds__(256) void gemm_nt(
    const unsigned short* __restrict__ A, const unsigned short* __restrict__ BT,
    const float* __restrict__ bias, const float* __restrict__ aux,
    void* __restrict__ Cout, int M, int N, int K) {
  __shared__ unsigned short As[128 * 32];
  __shared__ unsigned short Bs[128 * 32];
  const int tid = threadIdx.x;
  const int w = tid >> 6, l = tid & 63;
  const int m0 = blockIdx.x * 128, n0 = blockIdx.y * 128;
  const int r0 = w * 32 + (l >> 2);
  const int kof = (l & 3) * 8;
  const int lr = l & 15, lg = l >> 4;
  const int wr = (w >> 1) * 64, wc = (w & 1) * 64;
  f32x4 acc[4][4];
#pragma unroll
  for (int m = 0; m < 4; m++)
#pragma unroll
    for (int n = 0; n < 4; n++)
#pragma unroll
      for (int r = 0; r < 4; r++) acc[m][n][r] = 0.f;

  char* AsB = (char*)As; char* BsB = (char*)Bs;
  int ar0 = m0 + r0;      if (ar0 >= M) ar0 = M - 1;
  int ar1 = m0 + r0 + 16; if (ar1 >= M) ar1 = M - 1;
  const size_t a0 = (size_t)ar0 * K + kof;
  const size_t a1 = (size_t)ar1 * K + kof;
  const size_t b0 = (size_t)(n0 + r0) * K + kof;
  const size_t b1 = (size_t)(n0 + r0 + 16) * K + kof;

  for (int k0 = 0; k0 < K; k0 += 32) {
    __syncthreads();
    gload_lds16(A + a0 + k0, AsB + (w * 2 + 0) * 1024);
    gload_lds16(A + a1 + k0, AsB + (w * 2 + 1) * 1024);
    gload_lds16(BT + b0 + k0, BsB + (w * 2 + 0) * 1024);
    gload_lds16(BT + b1 + k0, BsB + (w * 2 + 1) * 1024);
    __syncthreads();
    s16x8 af[4], bf[4];
#pragma unroll
    for (int m = 0; m < 4; m++)
      af[m] = *(const s16x8*)(AsB + (wr + m * 16 + lr) * 64 + lg * 16);
#pragma unroll
    for (int n = 0; n < 4; n++)
      bf[n] = *(const s16x8*)(BsB + (wc + n * 16 + lr) * 64 + lg * 16);
#pragma unroll
    for (int m = 0; m < 4; m++)
#pragma unroll
      for (int n = 0; n < 4; n++)
        acc[m][n] = __builtin_amdgcn_mfma_f32_16x16x32_bf16(af[m], bf[n], acc[m][n], 0, 0, 0);
  }

  float bs[4];
#pragma unroll
  for (int n = 0; n < 4; n++) bs[n] = bias[n0 + wc + n * 16 + lr];
#pragma unroll
  for (int m = 0; m < 4; m++) {
#pragma unroll
    for (int r = 0; r < 4; r++) {
      int row = m0 + wr + m * 16 + lg * 4 + r;
      if (row >= M) continue;
      size_t rb = (size_t)row * N;
#pragma unroll
      for (int n = 0; n < 4; n++) {
        int col = n0 + wc + n * 16 + lr;
        float c = acc[m][n][r] + bs[n];
        if (EPI == 0) {
          ((unsigned short*)Cout)[rb + col] = f2bf(c);
        } else if (EPI == 1) {
          ((float*)Cout)[rb + col] = c + aux[rb + col];
        } else if (EPI == 2) {
          c = 0.5f * c * (1.f + erff(c * 0.70710678118f));
          ((unsigned short*)Cout)[rb + col] = f2bf(c);
        } else {
          ((float*)Cout)[rb + col] = c + aux[rb + col];   // f32 final output
        }
      }
    }
  }
}

// ---------------- flash attention: qkv bf16 [M,2304] -> attn bf16 [M,768] ----------------
// grid = 384 bh * 10 q-tiles; 4 waves, wave = 16 q-rows. Swapped QK^T (mfma(K,Q))
// so each lane owns one q-row's scores; V transposed into LDS for contiguous PV B-frags.
__global__ __launch_bounds__(256) void attn_kernel(const unsigned short* __restrict__ qkv,
                                                   unsigned short* __restrict__ out) {
  __shared__ unsigned short Pl[4 * 16 * 72];
  __shared__ unsigned short VT[64 * 72];
  const int tid = threadIdx.x;
  const int w = tid >> 6, l = tid & 63;
  const int lr = l & 15, lg = l >> 4;
  const int bh = blockIdx.x / 10, qt = blockIdx.x % 10;
  const int b = bh / NHEAD, h = bh % NHEAD;
  const size_t base = (size_t)b * 577 * 2304 + (size_t)h * 64;
  int qr = qt * 64 + w * 16 + lr; int qrc = qr > 576 ? 576 : qr;
  const unsigned short* qp = qkv + base + (size_t)qrc * 2304;
  const s16x8 qf0 = *(const s16x8*)(qp + lg * 8);
  const s16x8 qf1 = *(const s16x8*)(qp + 32 + lg * 8);
  f32x4 oacc[4];
#pragma unroll
  for (int d = 0; d < 4; d++)
#pragma unroll
    for (int r = 0; r < 4; r++) oacc[d][r] = 0.f;
  float mrun = -3e38f, lrun = 0.f;
  unsigned short* Pw = Pl + w * 16 * 72;

  for (int kt = 0; kt < 10; kt++) {
    __syncthreads();  // previous iteration's LDS reads complete
    // stage V^T: V[kc][d] -> VT[d][kc], 64x64 tile
#pragma unroll
    for (int c = 0; c < 2; c++) {
      int cid = c * 256 + tid;
      int kc = cid >> 3, d0 = (cid & 7) * 8;
      int vr = kt * 64 + kc; if (vr > 576) vr = 576;
      s16x8 vv = *(const s16x8*)(qkv + base + 1536 + (size_t)vr * 2304 + d0);
#pragma unroll
      for (int j = 0; j < 8; j++)
        VT[(d0 + j) * 72 + kc] = (unsigned short)vv[j];
    }
    // S^T = K * Q^T : lane holds S[q=lr][kc = sub*16 + lg*4 + r]
    float sv[16];
#pragma unroll
    for (int sub = 0; sub < 4; sub++) {
      int kc = kt * 64 + sub * 16 + lr; if (kc > 576) kc = 576;
      const unsigned short* kp = qkv + base + 768 + (size_t)kc * 2304;
      s16x8 kf0 = *(const s16x8*)(kp + lg * 8);
      s16x8 kf1 = *(const s16x8*)(kp + 32 + lg * 8);
      f32x4 st;
#pragma unroll
      for (int r = 0; r < 4; r++) st[r] = 0.f;
      st = __builtin_amdgcn_mfma_f32_16x16x32_bf16(kf0, qf0, st, 0, 0, 0);
      st = __builtin_amdgcn_mfma_f32_16x16x32_bf16(kf1, qf1, st, 0, 0, 0);
#pragma unroll
      for (int r = 0; r < 4; r++) {
        int kcg = kt * 64 + sub * 16 + lg * 4 + r;
        sv[sub * 4 + r] = (kcg <= 576) ? st[r] * 0.125f : -3e38f;
      }
    }
    // online softmax over this 64-wide tile
    float tm = sv[0];
#pragma unroll
    for (int i = 1; i < 16; i++) tm = fmaxf(tm, sv[i]);
    tm = fmaxf(tm, __shfl_xor(tm, 16));
    tm = fmaxf(tm, __shfl_xor(tm, 32));
    float mnew = fmaxf(mrun, tm);
    float fac = __expf(mrun - mnew);
    mrun = mnew;
    float ts = 0.f;
    unsigned short pb[16];
#pragma unroll
    for (int i = 0; i < 16; i++) {
      float p = __expf(sv[i] - mnew);
      ts += p;
      pb[i] = f2bf(p);
    }
    ts += __shfl_xor(ts, 16);
    ts += __shfl_xor(ts, 32);
    lrun = lrun * fac + ts;
    // P -> LDS [qr][kc] (stride 72)
#pragma unroll
    for (int sub = 0; sub < 4; sub++) {
      uint2 u;
      u.x = (unsigned)pb[sub * 4 + 0] | ((unsigned)pb[sub * 4 + 1] << 16);
      u.y = (unsigned)pb[sub * 4 + 2] | ((unsigned)pb[sub * 4 + 3] << 16);
      *(uint2*)(Pw + lr * 72 + sub * 16 + lg * 4) = u;
    }
    // rescale O by exp(m_old - m_new), redistributed to C-layout rows
    float fr[4];
#pragma unroll
    for (int r = 0; r < 4; r++) fr[r] = __shfl(fac, lg * 4 + r);
#pragma unroll
    for (int d = 0; d < 4; d++)
#pragma unroll
      for (int r = 0; r < 4; r++) oacc[d][r] *= fr[r];
    __syncthreads();  // VT + P visible
    // O += P * V
#pragma unroll
    for (int hf = 0; hf < 2; hf++) {
      s16x8 pf = *(const s16x8*)(Pw + lr * 72 + hf * 32 + lg * 8);
#pragma unroll
      for (int d = 0; d < 4; d++) {
        s16x8 vf = *(const s16x8*)(VT + (d * 16 + lr) * 72 + hf * 32 + lg * 8);
        oacc[d] = __builtin_amdgcn_mfma_f32_16x16x32_bf16(pf, vf, oacc[d], 0, 0, 0);
      }
    }
  }
  // epilogue: O / l, write bf16
#pragma unroll
  for (int r = 0; r < 4; r++) {
    int qg = qt * 64 + w * 16 + lg * 4 + r;
    if (qg > 576) continue;
    float inv = 1.f / __shfl(lrun, lg * 4 + r);
#pragma unroll
    for (int d = 0; d < 4; d++)
      out[(size_t)(b * 577 + qg) * 768 + h * 64 + d * 16 + lr] = f2bf(oacc[d][r] * inv);
  }
}

extern "C" void kernel_launch(void* const* d_in, const int* in_sizes, int n_in,
                              void* d_out, int out_size, void* d_ws, size_t ws_size,
                              hipStream_t stream) {
  const float* x      = (const float*)d_in[0];
  const float* w_qkv  = (const float*)d_in[1];
  const float* b_qkv  = (const float*)d_in[2];
  const float* w_proj = (const float*)d_in[3];
  const float* b_proj = (const float*)d_in[4];
  const float* g1  = (const float*)d_in[5];
  const float* be1 = (const float*)d_in[6];
  const float* g2  = (const float*)d_in[7];
  const float* be2 = (const float*)d_in[8];
  const float* g3  = (const float*)d_in[9];
  const float* be3 = (const float*)d_in[10];
  const float* w1  = (const float*)d_in[11];
  const float* bm1 = (const float*)d_in[12];
  const float* w2  = (const float*)d_in[13];
  const float* bm2 = (const float*)d_in[14];

  // workspace layout (bytes), total ~212.7 MB:
  //  [0,        3538944)  wqkvT   2304x768 bf16
  //  [3538944,  4718592)  wprojT   768x768 bf16
  //  [4718592,  9437184)  w1T     3072x768 bf16
  //  [9437184, 14155776)  w2T     768x3072 bf16
  //  [14155776,42516480)  hbuf    [M,768] bf16   (h1, then attnb, then h2)
  //  [42516480,155959296) qkv     [M,2304] bf16  (later hid [M,3072])
  //  [155959296,212680704) res1   [M,768] f32
  char* ws = (char*)d_ws;
  unsigned short* wqkvT  = (unsigned short*)(ws + 0);
  unsigned short* wprojT = (unsigned short*)(ws + 3538944);
  unsigned short* w1T    = (unsigned short*)(ws + 4718592);
  unsigned short* w2T    = (unsigned short*)(ws + 9437184);
  unsigned short* hbuf   = (unsigned short*)(ws + 14155776);
  unsigned short* qkv    = (unsigned short*)(ws + 42516480);
  unsigned short* hid    = qkv;
  unsigned short* attnb  = hbuf;   // alias: h1 dead after QKV GEMM
  float*          res1   = (float*)(ws + 155959296);

  dim3 b32(32, 8);
  wtrans<<<dim3(2304 / 32, 768 / 32),  b32, 0, stream>>>(w_qkv,  wqkvT,  768, 2304);
  wtrans<<<dim3(768 / 32, 768 / 32),   b32, 0, stream>>>(w_proj, wprojT, 768, 768);
  wtrans<<<dim3(3072 / 32, 768 / 32),  b32, 0, stream>>>(w1,     w1T,    768, 3072);
  wtrans<<<dim3(768 / 32, 3072 / 32),  b32, 0, stream>>>(w2,     w2T,    3072, 768);

  ln1_kernel<<<4616, 256, 0, stream>>>(x, g1, be1, hbuf);
  gemm_nt<0><<<dim3(145, 18), 256, 0, stream>>>(hbuf, wqkvT, b_qkv, nullptr, qkv, M_ROWS, 2304, 768);
  attn_kernel<<<3840, 256, 0, stream>>>(qkv, attnb);
  gemm_nt<1><<<dim3(145, 6), 256, 0, stream>>>(attnb, wprojT, b_proj, x, res1, M_ROWS, 768, 768);
  ln2_kernel<<<4616, 256, 0, stream>>>(res1, g2, be2, g3, be3, hbuf);
  gemm_nt<2><<<dim3(145, 24), 256, 0, stream>>>(hbuf, w1T, bm1, nullptr, hid, M_ROWS, 3072, 768);
  gemm_nt<3><<<dim3(145, 6), 256, 0, stream>>>(hid, w2T, bm2, res1, (float*)d_out, M_ROWS, 768, 3072);
}

// Round 9
// 848.536 us; speedup vs baseline: 5.7802x; 1.0322x over previous
//
#include <hip/hip_runtime.h>
#include <hip/hip_bf16.h>

// Encoder block, M = 32*577 = 18464 rows, D=768, H=12, HD=64, HID=3072.
// GEMMs bf16 MFMA (16x16x32), fp32 accumulate. Output d_out = FLOAT32.
// Round 9: single change vs round 8 = GEMM grid transposed (n = blockIdx.x
// fastest) so the n-blocks sharing one A-panel are dispatch-adjacent ->
// A fetched ~once from HBM (was re-streamed per n-slice: MLP2 FETCH 395 MB
// vs 175 MB minimal, HBM-bound at 27% MfmaUtil 18%).

#define M_ROWS 18464
#define NHEAD 12

typedef __attribute__((ext_vector_type(8))) short s16x8;
typedef __attribute__((ext_vector_type(4))) float f32x4;

__device__ __forceinline__ unsigned short f2bf(float f) {
  union { float f; unsigned u; } v; v.f = f;
  return (unsigned short)((v.u + 0x7fffu + ((v.u >> 16) & 1u)) >> 16);
}
__device__ __forceinline__ float bf2f(unsigned short h) {
  union { unsigned u; float f; } v; v.u = ((unsigned)h) << 16;
  return v.f;
}

__device__ __forceinline__ void gload_lds16(const void* g, void* l) {
  __builtin_amdgcn_global_load_lds((const __attribute__((address_space(1))) unsigned*)g,
                                   (__attribute__((address_space(3))) unsigned*)l, 16, 0, 0);
}

// ---------------- weight cast + transpose: f32 [K,N] -> bf16 [N,K] ----------------
__global__ __launch_bounds__(256) void wtrans(const float* __restrict__ in,
                                              unsigned short* __restrict__ out,
                                              int K, int N) {
  __shared__ float t[32][33];
  const int n0 = blockIdx.x * 32, k0 = blockIdx.y * 32;
  const int tx = threadIdx.x, ty = threadIdx.y;
  for (int i = ty; i < 32; i += 8)
    t[i][tx] = in[(size_t)(k0 + i) * N + n0 + tx];
  __syncthreads();
  for (int i = ty; i < 32; i += 8)
    out[(size_t)(n0 + i) * K + k0 + tx] = f2bf(t[tx][i]);
}

// ---------------- LayerNorm (1 wave per row), f32 in -> bf16 out ----------------
__global__ __launch_bounds__(256) void ln1_kernel(const float* __restrict__ x,
    const float* __restrict__ g, const float* __restrict__ be,
    unsigned short* __restrict__ out) {
  const int w = threadIdx.x >> 6, l = threadIdx.x & 63;
  const size_t row = (size_t)blockIdx.x * 4 + w;
  const float* xr = x + row * 768;
  f32x4 v[3];
#pragma unroll
  for (int s = 0; s < 3; s++) v[s] = ((const f32x4*)xr)[s * 64 + l];
  float sm = 0.f, sq = 0.f;
#pragma unroll
  for (int s = 0; s < 3; s++)
#pragma unroll
    for (int j = 0; j < 4; j++) { sm += v[s][j]; sq += v[s][j] * v[s][j]; }
#pragma unroll
  for (int o = 1; o < 64; o <<= 1) { sm += __shfl_xor(sm, o); sq += __shfl_xor(sq, o); }
  const float mean = sm * (1.f / 768.f);
  const float rs = rsqrtf(sq * (1.f / 768.f) - mean * mean + 1e-5f);
  unsigned short* orow = out + row * 768;
#pragma unroll
  for (int s = 0; s < 3; s++) {
    int col = s * 256 + l * 4;
    unsigned short h4[4];
#pragma unroll
    for (int j = 0; j < 4; j++)
      h4[j] = f2bf((v[s][j] - mean) * rs * g[col + j] + be[col + j]);
    uint2 u; u.x = h4[0] | ((unsigned)h4[1] << 16); u.y = h4[2] | ((unsigned)h4[3] << 16);
    *(uint2*)(orow + col) = u;
  }
}

// ---------------- double LayerNorm (LN(g2,be2) then LN(g3,be3)) ----------------
__global__ __launch_bounds__(256) void ln2_kernel(const float* __restrict__ xin,
    const float* __restrict__ g2, const float* __restrict__ be2,
    const float* __restrict__ g3, const float* __restrict__ be3,
    unsigned short* __restrict__ out) {
  const int w = threadIdx.x >> 6, l = threadIdx.x & 63;
  const size_t row = (size_t)blockIdx.x * 4 + w;
  const float* xr = xin + row * 768;
  f32x4 v[3];
#pragma unroll
  for (int s = 0; s < 3; s++) v[s] = ((const f32x4*)xr)[s * 64 + l];
  float sm = 0.f, sq = 0.f;
#pragma unroll
  for (int s = 0; s < 3; s++)
#pragma unroll
    for (int j = 0; j < 4; j++) { sm += v[s][j]; sq += v[s][j] * v[s][j]; }
#pragma unroll
  for (int o = 1; o < 64; o <<= 1) { sm += __shfl_xor(sm, o); sq += __shfl_xor(sq, o); }
  float mean = sm * (1.f / 768.f);
  float rs = rsqrtf(sq * (1.f / 768.f) - mean * mean + 1e-5f);
  float y[12];
  sm = 0.f; sq = 0.f;
#pragma unroll
  for (int s = 0; s < 3; s++) {
    int col = s * 256 + l * 4;
#pragma unroll
    for (int j = 0; j < 4; j++) {
      float t = (v[s][j] - mean) * rs * g2[col + j] + be2[col + j];
      y[s * 4 + j] = t; sm += t; sq += t * t;
    }
  }
#pragma unroll
  for (int o = 1; o < 64; o <<= 1) { sm += __shfl_xor(sm, o); sq += __shfl_xor(sq, o); }
  mean = sm * (1.f / 768.f);
  rs = rsqrtf(sq * (1.f / 768.f) - mean * mean + 1e-5f);
  unsigned short* orow = out + row * 768;
#pragma unroll
  for (int s = 0; s < 3; s++) {
    int col = s * 256 + l * 4;
    unsigned short h4[4];
#pragma unroll
    for (int j = 0; j < 4; j++)
      h4[j] = f2bf((y[s * 4 + j] - mean) * rs * g3[col + j] + be3[col + j]);
    uint2 u; u.x = h4[0] | ((unsigned)h4[1] << 16); u.y = h4[2] | ((unsigned)h4[3] << 16);
    *(uint2*)(orow + col) = u;
  }
}

// ---------------- NT GEMM: A[M,K] bf16 x BT[N,K] bf16 -> epilogue ----------------
// Grid: dim3(N/128, ceil(M/128)); n = blockIdx.x (fastest) for A-panel L2 reuse.
// EPI: 0 = +bias -> bf16 (QKV)
//      1 = +bias + aux(f32) -> f32 (proj: res1 = x + attn@W + b)
//      2 = +bias, exact GELU -> bf16 (MLP1)
//      3 = +bias + aux(f32) -> f32 (MLP2 -> d_out, f32 per reference dtype)
template<int EPI>
__global__ __launch_bounds__(256) void gemm_nt(
    const unsigned short* __restrict__ A, const unsigned short* __restrict__ BT,
    const float* __restrict__ bias, const float* __restrict__ aux,
    void* __restrict__ Cout, int M, int N, int K) {
  __shared__ unsigned short As[128 * 32];
  __shared__ unsigned short Bs[128 * 32];
  const int tid = threadIdx.x;
  const int w = tid >> 6, l = tid & 63;
  const int m0 = blockIdx.y * 128, n0 = blockIdx.x * 128;
  const int r0 = w * 32 + (l >> 2);
  const int kof = (l & 3) * 8;
  const int lr = l & 15, lg = l >> 4;
  const int wr = (w >> 1) * 64, wc = (w & 1) * 64;
  f32x4 acc[4][4];
#pragma unroll
  for (int m = 0; m < 4; m++)
#pragma unroll
    for (int n = 0; n < 4; n++)
#pragma unroll
      for (int r = 0; r < 4; r++) acc[m][n][r] = 0.f;

  char* AsB = (char*)As; char* BsB = (char*)Bs;
  int ar0 = m0 + r0;      if (ar0 >= M) ar0 = M - 1;
  int ar1 = m0 + r0 + 16; if (ar1 >= M) ar1 = M - 1;
  const size_t a0 = (size_t)ar0 * K + kof;
  const size_t a1 = (size_t)ar1 * K + kof;
  const size_t b0 = (size_t)(n0 + r0) * K + kof;
  const size_t b1 = (size_t)(n0 + r0 + 16) * K + kof;

  for (int k0 = 0; k0 < K; k0 += 32) {
    __syncthreads();
    gload_lds16(A + a0 + k0, AsB + (w * 2 + 0) * 1024);
    gload_lds16(A + a1 + k0, AsB + (w * 2 + 1) * 1024);
    gload_lds16(BT + b0 + k0, BsB + (w * 2 + 0) * 1024);
    gload_lds16(BT + b1 + k0, BsB + (w * 2 + 1) * 1024);
    __syncthreads();
    s16x8 af[4], bf[4];
#pragma unroll
    for (int m = 0; m < 4; m++)
      af[m] = *(const s16x8*)(AsB + (wr + m * 16 + lr) * 64 + lg * 16);
#pragma unroll
    for (int n = 0; n < 4; n++)
      bf[n] = *(const s16x8*)(BsB + (wc + n * 16 + lr) * 64 + lg * 16);
#pragma unroll
    for (int m = 0; m < 4; m++)
#pragma unroll
      for (int n = 0; n < 4; n++)
        acc[m][n] = __builtin_amdgcn_mfma_f32_16x16x32_bf16(af[m], bf[n], acc[m][n], 0, 0, 0);
  }

  float bs[4];
#pragma unroll
  for (int n = 0; n < 4; n++) bs[n] = bias[n0 + wc + n * 16 + lr];
#pragma unroll
  for (int m = 0; m < 4; m++) {
#pragma unroll
    for (int r = 0; r < 4; r++) {
      int row = m0 + wr + m * 16 + lg * 4 + r;
      if (row >= M) continue;
      size_t rb = (size_t)row * N;
#pragma unroll
      for (int n = 0; n < 4; n++) {
        int col = n0 + wc + n * 16 + lr;
        float c = acc[m][n][r] + bs[n];
        if (EPI == 0) {
          ((unsigned short*)Cout)[rb + col] = f2bf(c);
        } else if (EPI == 1) {
          ((float*)Cout)[rb + col] = c + aux[rb + col];
        } else if (EPI == 2) {
          c = 0.5f * c * (1.f + erff(c * 0.70710678118f));
          ((unsigned short*)Cout)[rb + col] = f2bf(c);
        } else {
          ((float*)Cout)[rb + col] = c + aux[rb + col];   // f32 final output
        }
      }
    }
  }
}

// ---------------- flash attention: qkv bf16 [M,2304] -> attn bf16 [M,768] ----------------
__global__ __launch_bounds__(256) void attn_kernel(const unsigned short* __restrict__ qkv,
                                                   unsigned short* __restrict__ out) {
  __shared__ unsigned short Pl[4 * 16 * 72];
  __shared__ unsigned short VT[64 * 72];
  const int tid = threadIdx.x;
  const int w = tid >> 6, l = tid & 63;
  const int lr = l & 15, lg = l >> 4;
  const int bh = blockIdx.x / 10, qt = blockIdx.x % 10;
  const int b = bh / NHEAD, h = bh % NHEAD;
  const size_t base = (size_t)b * 577 * 2304 + (size_t)h * 64;
  int qr = qt * 64 + w * 16 + lr; int qrc = qr > 576 ? 576 : qr;
  const unsigned short* qp = qkv + base + (size_t)qrc * 2304;
  const s16x8 qf0 = *(const s16x8*)(qp + lg * 8);
  const s16x8 qf1 = *(const s16x8*)(qp + 32 + lg * 8);
  f32x4 oacc[4];
#pragma unroll
  for (int d = 0; d < 4; d++)
#pragma unroll
    for (int r = 0; r < 4; r++) oacc[d][r] = 0.f;
  float mrun = -3e38f, lrun = 0.f;
  unsigned short* Pw = Pl + w * 16 * 72;

  for (int kt = 0; kt < 10; kt++) {
    __syncthreads();
#pragma unroll
    for (int c = 0; c < 2; c++) {
      int cid = c * 256 + tid;
      int kc = cid >> 3, d0 = (cid & 7) * 8;
      int vr = kt * 64 + kc; if (vr > 576) vr = 576;
      s16x8 vv = *(const s16x8*)(qkv + base + 1536 + (size_t)vr * 2304 + d0);
#pragma unroll
      for (int j = 0; j < 8; j++)
        VT[(d0 + j) * 72 + kc] = (unsigned short)vv[j];
    }
    float sv[16];
#pragma unroll
    for (int sub = 0; sub < 4; sub++) {
      int kc = kt * 64 + sub * 16 + lr; if (kc > 576) kc = 576;
      const unsigned short* kp = qkv + base + 768 + (size_t)kc * 2304;
      s16x8 kf0 = *(const s16x8*)(kp + lg * 8);
      s16x8 kf1 = *(const s16x8*)(kp + 32 + lg * 8);
      f32x4 st;
#pragma unroll
      for (int r = 0; r < 4; r++) st[r] = 0.f;
      st = __builtin_amdgcn_mfma_f32_16x16x32_bf16(kf0, qf0, st, 0, 0, 0);
      st = __builtin_amdgcn_mfma_f32_16x16x32_bf16(kf1, qf1, st, 0, 0, 0);
#pragma unroll
      for (int r = 0; r < 4; r++) {
        int kcg = kt * 64 + sub * 16 + lg * 4 + r;
        sv[sub * 4 + r] = (kcg <= 576) ? st[r] * 0.125f : -3e38f;
      }
    }
    float tm = sv[0];
#pragma unroll
    for (int i = 1; i < 16; i++) tm = fmaxf(tm, sv[i]);
    tm = fmaxf(tm, __shfl_xor(tm, 16));
    tm = fmaxf(tm, __shfl_xor(tm, 32));
    float mnew = fmaxf(mrun, tm);
    float fac = __expf(mrun - mnew);
    mrun = mnew;
    float ts = 0.f;
    unsigned short pb[16];
#pragma unroll
    for (int i = 0; i < 16; i++) {
      float p = __expf(sv[i] - mnew);
      ts += p;
      pb[i] = f2bf(p);
    }
    ts += __shfl_xor(ts, 16);
    ts += __shfl_xor(ts, 32);
    lrun = lrun * fac + ts;
#pragma unroll
    for (int sub = 0; sub < 4; sub++) {
      uint2 u;
      u.x = (unsigned)pb[sub * 4 + 0] | ((unsigned)pb[sub * 4 + 1] << 16);
      u.y = (unsigned)pb[sub * 4 + 2] | ((unsigned)pb[sub * 4 + 3] << 16);
      *(uint2*)(Pw + lr * 72 + sub * 16 + lg * 4) = u;
    }
    float fr[4];
#pragma unroll
    for (int r = 0; r < 4; r++) fr[r] = __shfl(fac, lg * 4 + r);
#pragma unroll
    for (int d = 0; d < 4; d++)
#pragma unroll
      for (int r = 0; r < 4; r++) oacc[d][r] *= fr[r];
    __syncthreads();
#pragma unroll
    for (int hf = 0; hf < 2; hf++) {
      s16x8 pf = *(const s16x8*)(Pw + lr * 72 + hf * 32 + lg * 8);
#pragma unroll
      for (int d = 0; d < 4; d++) {
        s16x8 vf = *(const s16x8*)(VT + (d * 16 + lr) * 72 + hf * 32 + lg * 8);
        oacc[d] = __builtin_amdgcn_mfma_f32_16x16x32_bf16(pf, vf, oacc[d], 0, 0, 0);
      }
    }
  }
#pragma unroll
  for (int r = 0; r < 4; r++) {
    int qg = qt * 64 + w * 16 + lg * 4 + r;
    if (qg > 576) continue;
    float inv = 1.f / __shfl(lrun, lg * 4 + r);
#pragma unroll
    for (int d = 0; d < 4; d++)
      out[(size_t)(b * 577 + qg) * 768 + h * 64 + d * 16 + lr] = f2bf(oacc[d][r] * inv);
  }
}

extern "C" void kernel_launch(void* const* d_in, const int* in_sizes, int n_in,
                              void* d_out, int out_size, void* d_ws, size_t ws_size,
                              hipStream_t stream) {
  const float* x      = (const float*)d_in[0];
  const float* w_qkv  = (const float*)d_in[1];
  const float* b_qkv  = (const float*)d_in[2];
  const float* w_proj = (const float*)d_in[3];
  const float* b_proj = (const float*)d_in[4];
  const float* g1  = (const float*)d_in[5];
  const float* be1 = (const float*)d_in[6];
  const float* g2  = (const float*)d_in[7];
  const float* be2 = (const float*)d_in[8];
  const float* g3  = (const float*)d_in[9];
  const float* be3 = (const float*)d_in[10];
  const float* w1  = (const float*)d_in[11];
  const float* bm1 = (const float*)d_in[12];
  const float* w2  = (const float*)d_in[13];
  const float* bm2 = (const float*)d_in[14];

  // workspace layout (bytes), total ~212.7 MB (see round-2 comment)
  char* ws = (char*)d_ws;
  unsigned short* wqkvT  = (unsigned short*)(ws + 0);
  unsigned short* wprojT = (unsigned short*)(ws + 3538944);
  unsigned short* w1T    = (unsigned short*)(ws + 4718592);
  unsigned short* w2T    = (unsigned short*)(ws + 9437184);
  unsigned short* hbuf   = (unsigned short*)(ws + 14155776);
  unsigned short* qkv    = (unsigned short*)(ws + 42516480);
  unsigned short* hid    = qkv;
  unsigned short* attnb  = hbuf;   // alias: h1 dead after QKV GEMM
  float*          res1   = (float*)(ws + 155959296);

  dim3 b32(32, 8);
  wtrans<<<dim3(2304 / 32, 768 / 32),  b32, 0, stream>>>(w_qkv,  wqkvT,  768, 2304);
  wtrans<<<dim3(768 / 32, 768 / 32),   b32, 0, stream>>>(w_proj, wprojT, 768, 768);
  wtrans<<<dim3(3072 / 32, 768 / 32),  b32, 0, stream>>>(w1,     w1T,    768, 3072);
  wtrans<<<dim3(768 / 32, 3072 / 32),  b32, 0, stream>>>(w2,     w2T,    3072, 768);

  ln1_kernel<<<4616, 256, 0, stream>>>(x, g1, be1, hbuf);
  // grid: (N/128, ceil(M/128)) -- n fastest for A-panel L2/L3 reuse
  gemm_nt<0><<<dim3(18, 145), 256, 0, stream>>>(hbuf, wqkvT, b_qkv, nullptr, qkv, M_ROWS, 2304, 768);
  attn_kernel<<<3840, 256, 0, stream>>>(qkv, attnb);
  gemm_nt<1><<<dim3(6, 145), 256, 0, stream>>>(attnb, wprojT, b_proj, x, res1, M_ROWS, 768, 768);
  ln2_kernel<<<4616, 256, 0, stream>>>(res1, g2, be2, g3, be3, hbuf);
  gemm_nt<2><<<dim3(24, 145), 256, 0, stream>>>(hbuf, w1T, bm1, nullptr, hid, M_ROWS, 3072, 768);
  gemm_nt<3><<<dim3(6, 145), 256, 0, stream>>>(hid, w2T, bm2, res1, (float*)d_out, M_ROWS, 768, 3072);
}

// Round 12
// 819.858 us; speedup vs baseline: 5.9824x; 1.0350x over previous
//
#include <hip/hip_runtime.h>
#include <hip/hip_bf16.h>

// Encoder block, M = 32*577 = 18464 rows, D=768, H=12, HD=64, HID=3072.
// GEMMs bf16 MFMA (16x16x32), fp32 accumulate. Output d_out = FLOAT32.
// Round 12: identical resubmit of round 10 (two infra timeouts, no signal).
//  (1) gemm_nt K-loop double-buffered: prefetch next tile via global_load_lds
//      BEFORE compute, single __syncthreads per step.
//  (2) bijective XCD-chunk swizzle (m204) so n-blocks sharing an A-panel run
//      on the SAME XCD's L2.

#define M_ROWS 18464
#define NHEAD 12

typedef __attribute__((ext_vector_type(8))) short s16x8;
typedef __attribute__((ext_vector_type(4))) float f32x4;

__device__ __forceinline__ unsigned short f2bf(float f) {
  union { float f; unsigned u; } v; v.f = f;
  return (unsigned short)((v.u + 0x7fffu + ((v.u >> 16) & 1u)) >> 16);
}
__device__ __forceinline__ float bf2f(unsigned short h) {
  union { unsigned u; float f; } v; v.u = ((unsigned)h) << 16;
  return v.f;
}

__device__ __forceinline__ void gload_lds16(const void* g, void* l) {
  __builtin_amdgcn_global_load_lds((const __attribute__((address_space(1))) unsigned*)g,
                                   (__attribute__((address_space(3))) unsigned*)l, 16, 0, 0);
}

// ---------------- weight cast + transpose: f32 [K,N] -> bf16 [N,K] ----------------
__global__ __launch_bounds__(256) void wtrans(const float* __restrict__ in,
                                              unsigned short* __restrict__ out,
                                              int K, int N) {
  __shared__ float t[32][33];
  const int n0 = blockIdx.x * 32, k0 = blockIdx.y * 32;
  const int tx = threadIdx.x, ty = threadIdx.y;
  for (int i = ty; i < 32; i += 8)
    t[i][tx] = in[(size_t)(k0 + i) * N + n0 + tx];
  __syncthreads();
  for (int i = ty; i < 32; i += 8)
    out[(size_t)(n0 + i) * K + k0 + tx] = f2bf(t[tx][i]);
}

// ---------------- LayerNorm (1 wave per row), f32 in -> bf16 out ----------------
__global__ __launch_bounds__(256) void ln1_kernel(const float* __restrict__ x,
    const float* __restrict__ g, const float* __restrict__ be,
    unsigned short* __restrict__ out) {
  const int w = threadIdx.x >> 6, l = threadIdx.x & 63;
  const size_t row = (size_t)blockIdx.x * 4 + w;
  const float* xr = x + row * 768;
  f32x4 v[3];
#pragma unroll
  for (int s = 0; s < 3; s++) v[s] = ((const f32x4*)xr)[s * 64 + l];
  float sm = 0.f, sq = 0.f;
#pragma unroll
  for (int s = 0; s < 3; s++)
#pragma unroll
    for (int j = 0; j < 4; j++) { sm += v[s][j]; sq += v[s][j] * v[s][j]; }
#pragma unroll
  for (int o = 1; o < 64; o <<= 1) { sm += __shfl_xor(sm, o); sq += __shfl_xor(sq, o); }
  const float mean = sm * (1.f / 768.f);
  const float rs = rsqrtf(sq * (1.f / 768.f) - mean * mean + 1e-5f);
  unsigned short* orow = out + row * 768;
#pragma unroll
  for (int s = 0; s < 3; s++) {
    int col = s * 256 + l * 4;
    unsigned short h4[4];
#pragma unroll
    for (int j = 0; j < 4; j++)
      h4[j] = f2bf((v[s][j] - mean) * rs * g[col + j] + be[col + j]);
    uint2 u; u.x = h4[0] | ((unsigned)h4[1] << 16); u.y = h4[2] | ((unsigned)h4[3] << 16);
    *(uint2*)(orow + col) = u;
  }
}

// ---------------- double LayerNorm (LN(g2,be2) then LN(g3,be3)) ----------------
__global__ __launch_bounds__(256) void ln2_kernel(const float* __restrict__ xin,
    const float* __restrict__ g2, const float* __restrict__ be2,
    const float* __restrict__ g3, const float* __restrict__ be3,
    unsigned short* __restrict__ out) {
  const int w = threadIdx.x >> 6, l = threadIdx.x & 63;
  const size_t row = (size_t)blockIdx.x * 4 + w;
  const float* xr = xin + row * 768;
  f32x4 v[3];
#pragma unroll
  for (int s = 0; s < 3; s++) v[s] = ((const f32x4*)xr)[s * 64 + l];
  float sm = 0.f, sq = 0.f;
#pragma unroll
  for (int s = 0; s < 3; s++)
#pragma unroll
    for (int j = 0; j < 4; j++) { sm += v[s][j]; sq += v[s][j] * v[s][j]; }
#pragma unroll
  for (int o = 1; o < 64; o <<= 1) { sm += __shfl_xor(sm, o); sq += __shfl_xor(sq, o); }
  float mean = sm * (1.f / 768.f);
  float rs = rsqrtf(sq * (1.f / 768.f) - mean * mean + 1e-5f);
  float y[12];
  sm = 0.f; sq = 0.f;
#pragma unroll
  for (int s = 0; s < 3; s++) {
    int col = s * 256 + l * 4;
#pragma unroll
    for (int j = 0; j < 4; j++) {
      float t = (v[s][j] - mean) * rs * g2[col + j] + be2[col + j];
      y[s * 4 + j] = t; sm += t; sq += t * t;
    }
  }
#pragma unroll
  for (int o = 1; o < 64; o <<= 1) { sm += __shfl_xor(sm, o); sq += __shfl_xor(sq, o); }
  mean = sm * (1.f / 768.f);
  rs = rsqrtf(sq * (1.f / 768.f) - mean * mean + 1e-5f);
  unsigned short* orow = out + row * 768;
#pragma unroll
  for (int s = 0; s < 3; s++) {
    int col = s * 256 + l * 4;
    unsigned short h4[4];
#pragma unroll
    for (int j = 0; j < 4; j++)
      h4[j] = f2bf((y[s * 4 + j] - mean) * rs * g3[col + j] + be3[col + j]);
    uint2 u; u.x = h4[0] | ((unsigned)h4[1] << 16); u.y = h4[2] | ((unsigned)h4[3] << 16);
    *(uint2*)(orow + col) = u;
  }
}

// ---------------- NT GEMM: A[M,K] bf16 x BT[N,K] bf16 -> epilogue ----------------
// Grid: dim3(N/128, ceil(M/128)). Double-buffered LDS, 1 barrier per K-step,
// bijective XCD-chunk swizzle for A-panel L2 reuse.
// EPI: 0 = +bias -> bf16 (QKV)
//      1 = +bias + aux(f32) -> f32 (proj: res1 = x + attn@W + b)
//      2 = +bias, exact GELU -> bf16 (MLP1)
//      3 = +bias + aux(f32) -> f32 (MLP2 -> d_out)
template<int EPI>
__global__ __launch_bounds__(256) void gemm_nt(
    const unsigned short* __restrict__ A, const unsigned short* __restrict__ BT,
    const float* __restrict__ bias, const float* __restrict__ aux,
    void* __restrict__ Cout, int M, int N, int K) {
  __shared__ unsigned short As[2][128 * 32];
  __shared__ unsigned short Bs[2][128 * 32];
  const int tid = threadIdx.x;
  const int w = tid >> 6, l = tid & 63;
  // --- bijective XCD-chunk swizzle (m204): orig%8 = XCD; give each XCD a
  //     contiguous chunk of the (x-fastest) block space so blocks sharing an
  //     A-panel co-locate on one XCD L2.
  const int gx = (int)gridDim.x;
  const int nwg = gx * (int)gridDim.y;
  const int orig = (int)blockIdx.y * gx + (int)blockIdx.x;
  const int q = nwg >> 3, r = nwg & 7, xcd = orig & 7, slot = orig >> 3;
  const int newid = (xcd < r ? xcd * (q + 1) : r * (q + 1) + (xcd - r) * q) + slot;
  const int m0 = (newid / gx) * 128, n0 = (newid % gx) * 128;

  const int r0 = w * 32 + (l >> 2);
  const int kof = (l & 3) * 8;
  const int lr = l & 15, lg = l >> 4;
  const int wr = (w >> 1) * 64, wc = (w & 1) * 64;
  const int woff = w * 2048;           // byte offset of this wave's staging pair
  f32x4 acc[4][4];
#pragma unroll
  for (int m = 0; m < 4; m++)
#pragma unroll
    for (int n = 0; n < 4; n++)
#pragma unroll
      for (int r4 = 0; r4 < 4; r4++) acc[m][n][r4] = 0.f;

  int ar0 = m0 + r0;      if (ar0 >= M) ar0 = M - 1;
  int ar1 = m0 + r0 + 16; if (ar1 >= M) ar1 = M - 1;
  const size_t a0 = (size_t)ar0 * K + kof;
  const size_t a1 = (size_t)ar1 * K + kof;
  const size_t b0 = (size_t)(n0 + r0) * K + kof;
  const size_t b1 = (size_t)(n0 + r0 + 16) * K + kof;

  // prologue: stage tile 0 into buffer 0
  gload_lds16(A + a0, (char*)As[0] + woff);
  gload_lds16(A + a1, (char*)As[0] + woff + 1024);
  gload_lds16(BT + b0, (char*)Bs[0] + woff);
  gload_lds16(BT + b1, (char*)Bs[0] + woff + 1024);
  __syncthreads();   // drains vmcnt(0): buffer 0 valid

  int cur = 0;
  for (int k0 = 0; k0 < K; k0 += 32) {
    const int kn = k0 + 32;
    if (kn < K) {    // prefetch next tile into the other buffer (overlaps compute)
      gload_lds16(A + a0 + kn, (char*)As[cur ^ 1] + woff);
      gload_lds16(A + a1 + kn, (char*)As[cur ^ 1] + woff + 1024);
      gload_lds16(BT + b0 + kn, (char*)Bs[cur ^ 1] + woff);
      gload_lds16(BT + b1 + kn, (char*)Bs[cur ^ 1] + woff + 1024);
    }
    const char* AsB = (const char*)As[cur];
    const char* BsB = (const char*)Bs[cur];
    s16x8 af[4], bf[4];
#pragma unroll
    for (int m = 0; m < 4; m++)
      af[m] = *(const s16x8*)(AsB + (wr + m * 16 + lr) * 64 + lg * 16);
#pragma unroll
    for (int n = 0; n < 4; n++)
      bf[n] = *(const s16x8*)(BsB + (wc + n * 16 + lr) * 64 + lg * 16);
#pragma unroll
    for (int m = 0; m < 4; m++)
#pragma unroll
      for (int n = 0; n < 4; n++)
        acc[m][n] = __builtin_amdgcn_mfma_f32_16x16x32_bf16(af[m], bf[n], acc[m][n], 0, 0, 0);
    __syncthreads();  // drains prefetch (vmcnt 0) + all waves done reading cur
    cur ^= 1;
  }

  float bs[4];
#pragma unroll
  for (int n = 0; n < 4; n++) bs[n] = bias[n0 + wc + n * 16 + lr];
#pragma unroll
  for (int m = 0; m < 4; m++) {
#pragma unroll
    for (int r4 = 0; r4 < 4; r4++) {
      int row = m0 + wr + m * 16 + lg * 4 + r4;
      if (row >= M) continue;
      size_t rb = (size_t)row * N;
#pragma unroll
      for (int n = 0; n < 4; n++) {
        int col = n0 + wc + n * 16 + lr;
        float c = acc[m][n][r4] + bs[n];
        if (EPI == 0) {
          ((unsigned short*)Cout)[rb + col] = f2bf(c);
        } else if (EPI == 1) {
          ((float*)Cout)[rb + col] = c + aux[rb + col];
        } else if (EPI == 2) {
          c = 0.5f * c * (1.f + erff(c * 0.70710678118f));
          ((unsigned short*)Cout)[rb + col] = f2bf(c);
        } else {
          ((float*)Cout)[rb + col] = c + aux[rb + col];   // f32 final output
        }
      }
    }
  }
}

// ---------------- flash attention: qkv bf16 [M,2304] -> attn bf16 [M,768] ----------------
__global__ __launch_bounds__(256) void attn_kernel(const unsigned short* __restrict__ qkv,
                                                   unsigned short* __restrict__ out) {
  __shared__ unsigned short Pl[4 * 16 * 72];
  __shared__ unsigned short VT[64 * 72];
  const int tid = threadIdx.x;
  const int w = tid >> 6, l = tid & 63;
  const int lr = l & 15, lg = l >> 4;
  const int bh = blockIdx.x / 10, qt = blockIdx.x % 10;
  const int b = bh / NHEAD, h = bh % NHEAD;
  const size_t base = (size_t)b * 577 * 2304 + (size_t)h * 64;
  int qr = qt * 64 + w * 16 + lr; int qrc = qr > 576 ? 576 : qr;
  const unsigned short* qp = qkv + base + (size_t)qrc * 2304;
  const s16x8 qf0 = *(const s16x8*)(qp + lg * 8);
  const s16x8 qf1 = *(const s16x8*)(qp + 32 + lg * 8);
  f32x4 oacc[4];
#pragma unroll
  for (int d = 0; d < 4; d++)
#pragma unroll
    for (int r = 0; r < 4; r++) oacc[d][r] = 0.f;
  float mrun = -3e38f, lrun = 0.f;
  unsigned short* Pw = Pl + w * 16 * 72;

  for (int kt = 0; kt < 10; kt++) {
    __syncthreads();
#pragma unroll
    for (int c = 0; c < 2; c++) {
      int cid = c * 256 + tid;
      int kc = cid >> 3, d0 = (cid & 7) * 8;
      int vr = kt * 64 + kc; if (vr > 576) vr = 576;
      s16x8 vv = *(const s16x8*)(qkv + base + 1536 + (size_t)vr * 2304 + d0);
#pragma unroll
      for (int j = 0; j < 8; j++)
        VT[(d0 + j) * 72 + kc] = (unsigned short)vv[j];
    }
    float sv[16];
#pragma unroll
    for (int sub = 0; sub < 4; sub++) {
      int kc = kt * 64 + sub * 16 + lr; if (kc > 576) kc = 576;
      const unsigned short* kp = qkv + base + 768 + (size_t)kc * 2304;
      s16x8 kf0 = *(const s16x8*)(kp + lg * 8);
      s16x8 kf1 = *(const s16x8*)(kp + 32 + lg * 8);
      f32x4 st;
#pragma unroll
      for (int r = 0; r < 4; r++) st[r] = 0.f;
      st = __builtin_amdgcn_mfma_f32_16x16x32_bf16(kf0, qf0, st, 0, 0, 0);
      st = __builtin_amdgcn_mfma_f32_16x16x32_bf16(kf1, qf1, st, 0, 0, 0);
#pragma unroll
      for (int r = 0; r < 4; r++) {
        int kcg = kt * 64 + sub * 16 + lg * 4 + r;
        sv[sub * 4 + r] = (kcg <= 576) ? st[r] * 0.125f : -3e38f;
      }
    }
    float tm = sv[0];
#pragma unroll
    for (int i = 1; i < 16; i++) tm = fmaxf(tm, sv[i]);
    tm = fmaxf(tm, __shfl_xor(tm, 16));
    tm = fmaxf(tm, __shfl_xor(tm, 32));
    float mnew = fmaxf(mrun, tm);
    float fac = __expf(mrun - mnew);
    mrun = mnew;
    float ts = 0.f;
    unsigned short pb[16];
#pragma unroll
    for (int i = 0; i < 16; i++) {
      float p = __expf(sv[i] - mnew);
      ts += p;
      pb[i] = f2bf(p);
    }
    ts += __shfl_xor(ts, 16);
    ts += __shfl_xor(ts, 32);
    lrun = lrun * fac + ts;
#pragma unroll
    for (int sub = 0; sub < 4; sub++) {
      uint2 u;
      u.x = (unsigned)pb[sub * 4 + 0] | ((unsigned)pb[sub * 4 + 1] << 16);
      u.y = (unsigned)pb[sub * 4 + 2] | ((unsigned)pb[sub * 4 + 3] << 16);
      *(uint2*)(Pw + lr * 72 + sub * 16 + lg * 4) = u;
    }
    float fr[4];
#pragma unroll
    for (int r = 0; r < 4; r++) fr[r] = __shfl(fac, lg * 4 + r);
#pragma unroll
    for (int d = 0; d < 4; d++)
#pragma unroll
      for (int r = 0; r < 4; r++) oacc[d][r] *= fr[r];
    __syncthreads();
#pragma unroll
    for (int hf = 0; hf < 2; hf++) {
      s16x8 pf = *(const s16x8*)(Pw + lr * 72 + hf * 32 + lg * 8);
#pragma unroll
      for (int d = 0; d < 4; d++) {
        s16x8 vf = *(const s16x8*)(VT + (d * 16 + lr) * 72 + hf * 32 + lg * 8);
        oacc[d] = __builtin_amdgcn_mfma_f32_16x16x32_bf16(pf, vf, oacc[d], 0, 0, 0);
      }
    }
  }
#pragma unroll
  for (int r = 0; r < 4; r++) {
    int qg = qt * 64 + w * 16 + lg * 4 + r;
    if (qg > 576) continue;
    float inv = 1.f / __shfl(lrun, lg * 4 + r);
#pragma unroll
    for (int d = 0; d < 4; d++)
      out[(size_t)(b * 577 + qg) * 768 + h * 64 + d * 16 + lr] = f2bf(oacc[d][r] * inv);
  }
}

extern "C" void kernel_launch(void* const* d_in, const int* in_sizes, int n_in,
                              void* d_out, int out_size, void* d_ws, size_t ws_size,
                              hipStream_t stream) {
  const float* x      = (const float*)d_in[0];
  const float* w_qkv  = (const float*)d_in[1];
  const float* b_qkv  = (const float*)d_in[2];
  const float* w_proj = (const float*)d_in[3];
  const float* b_proj = (const float*)d_in[4];
  const float* g1  = (const float*)d_in[5];
  const float* be1 = (const float*)d_in[6];
  const float* g2  = (const float*)d_in[7];
  const float* be2 = (const float*)d_in[8];
  const float* g3  = (const float*)d_in[9];
  const float* be3 = (const float*)d_in[10];
  const float* w1  = (const float*)d_in[11];
  const float* bm1 = (const float*)d_in[12];
  const float* w2  = (const float*)d_in[13];
  const float* bm2 = (const float*)d_in[14];

  // workspace layout (bytes), total ~212.7 MB (see round-2 comment)
  char* ws = (char*)d_ws;
  unsigned short* wqkvT  = (unsigned short*)(ws + 0);
  unsigned short* wprojT = (unsigned short*)(ws + 3538944);
  unsigned short* w1T    = (unsigned short*)(ws + 4718592);
  unsigned short* w2T    = (unsigned short*)(ws + 9437184);
  unsigned short* hbuf   = (unsigned short*)(ws + 14155776);
  unsigned short* qkv    = (unsigned short*)(ws + 42516480);
  unsigned short* hid    = qkv;
  unsigned short* attnb  = hbuf;   // alias: h1 dead after QKV GEMM
  float*          res1   = (float*)(ws + 155959296);

  dim3 b32(32, 8);
  wtrans<<<dim3(2304 / 32, 768 / 32),  b32, 0, stream>>>(w_qkv,  wqkvT,  768, 2304);
  wtrans<<<dim3(768 / 32, 768 / 32),   b32, 0, stream>>>(w_proj, wprojT, 768, 768);
  wtrans<<<dim3(3072 / 32, 768 / 32),  b32, 0, stream>>>(w1,     w1T,    768, 3072);
  wtrans<<<dim3(768 / 32, 3072 / 32),  b32, 0, stream>>>(w2,     w2T,    3072, 768);

  ln1_kernel<<<4616, 256, 0, stream>>>(x, g1, be1, hbuf);
  gemm_nt<0><<<dim3(18, 145), 256, 0, stream>>>(hbuf, wqkvT, b_qkv, nullptr, qkv, M_ROWS, 2304, 768);
  attn_kernel<<<3840, 256, 0, stream>>>(qkv, attnb);
  gemm_nt<1><<<dim3(6, 145), 256, 0, stream>>>(attnb, wprojT, b_proj, x, res1, M_ROWS, 768, 768);
  ln2_kernel<<<4616, 256, 0, stream>>>(res1, g2, be2, g3, be3, hbuf);
  gemm_nt<2><<<dim3(24, 145), 256, 0, stream>>>(hbuf, w1T, bm1, nullptr, hid, M_ROWS, 3072, 768);
  gemm_nt<3><<<dim3(6, 145), 256, 0, stream>>>(hid, w2T, bm2, res1, (float*)d_out, M_ROWS, 768, 3072);
}

// Round 13
// 807.504 us; speedup vs baseline: 6.0739x; 1.0153x over previous
//
#include <hip/hip_runtime.h>
#include <hip/hip_bf16.h>

// Encoder block, M = 32*577 = 18464 rows, D=768, H=12, HD=64, HID=3072.
// GEMMs bf16 MFMA (16x16x32), fp32 accumulate. Output d_out = FLOAT32.
// Round 13 vs round 12 (single mechanism: T4 counted vmcnt):
//   gemm_nt: triple-buffered LDS (48 KB), prefetch 2 tiles ahead, raw
//   s_barrier + counted s_waitcnt vmcnt(8/4/0) so global_load_lds stays in
//   flight across barriers (round-12 __syncthreads drained vmcnt(0) every
//   K-step -> latency-bound: MfmaUtil 18.6%, VALUBusy 11%, HBM 12%).

#define M_ROWS 18464
#define NHEAD 12

typedef __attribute__((ext_vector_type(8))) short s16x8;
typedef __attribute__((ext_vector_type(4))) float f32x4;

__device__ __forceinline__ unsigned short f2bf(float f) {
  union { float f; unsigned u; } v; v.f = f;
  return (unsigned short)((v.u + 0x7fffu + ((v.u >> 16) & 1u)) >> 16);
}
__device__ __forceinline__ float bf2f(unsigned short h) {
  union { unsigned u; float f; } v; v.u = ((unsigned)h) << 16;
  return v.f;
}

__device__ __forceinline__ void gload_lds16(const void* g, void* l) {
  __builtin_amdgcn_global_load_lds((const __attribute__((address_space(1))) unsigned*)g,
                                   (__attribute__((address_space(3))) unsigned*)l, 16, 0, 0);
}

// ---------------- weight cast + transpose: f32 [K,N] -> bf16 [N,K] ----------------
__global__ __launch_bounds__(256) void wtrans(const float* __restrict__ in,
                                              unsigned short* __restrict__ out,
                                              int K, int N) {
  __shared__ float t[32][33];
  const int n0 = blockIdx.x * 32, k0 = blockIdx.y * 32;
  const int tx = threadIdx.x, ty = threadIdx.y;
  for (int i = ty; i < 32; i += 8)
    t[i][tx] = in[(size_t)(k0 + i) * N + n0 + tx];
  __syncthreads();
  for (int i = ty; i < 32; i += 8)
    out[(size_t)(n0 + i) * K + k0 + tx] = f2bf(t[tx][i]);
}

// ---------------- LayerNorm (1 wave per row), f32 in -> bf16 out ----------------
__global__ __launch_bounds__(256) void ln1_kernel(const float* __restrict__ x,
    const float* __restrict__ g, const float* __restrict__ be,
    unsigned short* __restrict__ out) {
  const int w = threadIdx.x >> 6, l = threadIdx.x & 63;
  const size_t row = (size_t)blockIdx.x * 4 + w;
  const float* xr = x + row * 768;
  f32x4 v[3];
#pragma unroll
  for (int s = 0; s < 3; s++) v[s] = ((const f32x4*)xr)[s * 64 + l];
  float sm = 0.f, sq = 0.f;
#pragma unroll
  for (int s = 0; s < 3; s++)
#pragma unroll
    for (int j = 0; j < 4; j++) { sm += v[s][j]; sq += v[s][j] * v[s][j]; }
#pragma unroll
  for (int o = 1; o < 64; o <<= 1) { sm += __shfl_xor(sm, o); sq += __shfl_xor(sq, o); }
  const float mean = sm * (1.f / 768.f);
  const float rs = rsqrtf(sq * (1.f / 768.f) - mean * mean + 1e-5f);
  unsigned short* orow = out + row * 768;
#pragma unroll
  for (int s = 0; s < 3; s++) {
    int col = s * 256 + l * 4;
    unsigned short h4[4];
#pragma unroll
    for (int j = 0; j < 4; j++)
      h4[j] = f2bf((v[s][j] - mean) * rs * g[col + j] + be[col + j]);
    uint2 u; u.x = h4[0] | ((unsigned)h4[1] << 16); u.y = h4[2] | ((unsigned)h4[3] << 16);
    *(uint2*)(orow + col) = u;
  }
}

// ---------------- double LayerNorm (LN(g2,be2) then LN(g3,be3)) ----------------
__global__ __launch_bounds__(256) void ln2_kernel(const float* __restrict__ xin,
    const float* __restrict__ g2, const float* __restrict__ be2,
    const float* __restrict__ g3, const float* __restrict__ be3,
    unsigned short* __restrict__ out) {
  const int w = threadIdx.x >> 6, l = threadIdx.x & 63;
  const size_t row = (size_t)blockIdx.x * 4 + w;
  const float* xr = xin + row * 768;
  f32x4 v[3];
#pragma unroll
  for (int s = 0; s < 3; s++) v[s] = ((const f32x4*)xr)[s * 64 + l];
  float sm = 0.f, sq = 0.f;
#pragma unroll
  for (int s = 0; s < 3; s++)
#pragma unroll
    for (int j = 0; j < 4; j++) { sm += v[s][j]; sq += v[s][j] * v[s][j]; }
#pragma unroll
  for (int o = 1; o < 64; o <<= 1) { sm += __shfl_xor(sm, o); sq += __shfl_xor(sq, o); }
  float mean = sm * (1.f / 768.f);
  float rs = rsqrtf(sq * (1.f / 768.f) - mean * mean + 1e-5f);
  float y[12];
  sm = 0.f; sq = 0.f;
#pragma unroll
  for (int s = 0; s < 3; s++) {
    int col = s * 256 + l * 4;
#pragma unroll
    for (int j = 0; j < 4; j++) {
      float t = (v[s][j] - mean) * rs * g2[col + j] + be2[col + j];
      y[s * 4 + j] = t; sm += t; sq += t * t;
    }
  }
#pragma unroll
  for (int o = 1; o < 64; o <<= 1) { sm += __shfl_xor(sm, o); sq += __shfl_xor(sq, o); }
  mean = sm * (1.f / 768.f);
  rs = rsqrtf(sq * (1.f / 768.f) - mean * mean + 1e-5f);
  unsigned short* orow = out + row * 768;
#pragma unroll
  for (int s = 0; s < 3; s++) {
    int col = s * 256 + l * 4;
    unsigned short h4[4];
#pragma unroll
    for (int j = 0; j < 4; j++)
      h4[j] = f2bf((y[s * 4 + j] - mean) * rs * g3[col + j] + be3[col + j]);
    uint2 u; u.x = h4[0] | ((unsigned)h4[1] << 16); u.y = h4[2] | ((unsigned)h4[3] << 16);
    *(uint2*)(orow + col) = u;
  }
}

// ---------------- NT GEMM: A[M,K] bf16 x BT[N,K] bf16 -> epilogue ----------------
// Grid: dim3(N/128, ceil(M/128)). Triple-buffered LDS, counted-vmcnt pipeline
// (2 tiles prefetched ahead; vmcnt never drained to 0 in steady state),
// bijective XCD-chunk swizzle for A-panel L2 reuse.
// EPI: 0 = +bias -> bf16 (QKV)
//      1 = +bias + aux(f32) -> f32 (proj: res1 = x + attn@W + b)
//      2 = +bias, exact GELU -> bf16 (MLP1)
//      3 = +bias + aux(f32) -> f32 (MLP2 -> d_out)
template<int EPI>
__global__ __launch_bounds__(256) void gemm_nt(
    const unsigned short* __restrict__ A, const unsigned short* __restrict__ BT,
    const float* __restrict__ bias, const float* __restrict__ aux,
    void* __restrict__ Cout, int M, int N, int K) {
  __shared__ unsigned short As[3][128 * 32];   // 24 KB
  __shared__ unsigned short Bs[3][128 * 32];   // 24 KB
  const int tid = threadIdx.x;
  const int w = tid >> 6, l = tid & 63;
  // bijective XCD-chunk swizzle (m204)
  const int gx = (int)gridDim.x;
  const int nwg = gx * (int)gridDim.y;
  const int orig = (int)blockIdx.y * gx + (int)blockIdx.x;
  const int q = nwg >> 3, r = nwg & 7, xcd = orig & 7, slot = orig >> 3;
  const int newid = (xcd < r ? xcd * (q + 1) : r * (q + 1) + (xcd - r) * q) + slot;
  const int m0 = (newid / gx) * 128, n0 = (newid % gx) * 128;

  const int r0 = w * 32 + (l >> 2);
  const int kof = (l & 3) * 8;
  const int lr = l & 15, lg = l >> 4;
  const int wr = (w >> 1) * 64, wc = (w & 1) * 64;
  const int woff = w * 2048;           // wave's 2KB staging region within a buffer
  f32x4 acc[4][4];
#pragma unroll
  for (int m = 0; m < 4; m++)
#pragma unroll
    for (int n = 0; n < 4; n++)
#pragma unroll
      for (int r4 = 0; r4 < 4; r4++) acc[m][n][r4] = 0.f;

  int ar0 = m0 + r0;      if (ar0 >= M) ar0 = M - 1;
  int ar1 = m0 + r0 + 16; if (ar1 >= M) ar1 = M - 1;
  const size_t a0 = (size_t)ar0 * K + kof;
  const size_t a1 = (size_t)ar1 * K + kof;
  const size_t b0 = (size_t)(n0 + r0) * K + kof;
  const size_t b1 = (size_t)(n0 + r0 + 16) * K + kof;

  const int nt = K >> 5;   // K/32 tiles (K is 768 or 3072: nt = 24 or 96)
  // prologue: stage tiles 0..2 into buffers 0..2 (12 loads in flight/wave)
#pragma unroll
  for (int t = 0; t < 3; t++) {
    const int kk = t << 5;
    char* ab = (char*)As + t * 8192 + woff;
    char* bb = (char*)Bs + t * 8192 + woff;
    gload_lds16(A + a0 + kk, ab);
    gload_lds16(A + a1 + kk, ab + 1024);
    gload_lds16(BT + b0 + kk, bb);
    gload_lds16(BT + b1 + kk, bb + 1024);
  }

  for (int t = 0; t < nt; t++) {
    // wait for THIS tile's 4 loads (others stay in flight), then sync
    if (t < nt - 2)       asm volatile("s_waitcnt vmcnt(8)" ::: "memory");
    else if (t == nt - 2) asm volatile("s_waitcnt vmcnt(4)" ::: "memory");
    else                  asm volatile("s_waitcnt vmcnt(0)" ::: "memory");
    __builtin_amdgcn_s_barrier();      // all waves' tile-t staging complete

    const int buf = t - (t / 3) * 3;   // t % 3
    const char* AsB = (const char*)As + buf * 8192;
    const char* BsB = (const char*)Bs + buf * 8192;
    s16x8 af[4], bf[4];
#pragma unroll
    for (int m = 0; m < 4; m++)
      af[m] = *(const s16x8*)(AsB + (wr + m * 16 + lr) * 64 + lg * 16);
#pragma unroll
    for (int n = 0; n < 4; n++)
      bf[n] = *(const s16x8*)(BsB + (wc + n * 16 + lr) * 64 + lg * 16);
#pragma unroll
    for (int m = 0; m < 4; m++)
#pragma unroll
      for (int n = 0; n < 4; n++)
        acc[m][n] = __builtin_amdgcn_mfma_f32_16x16x32_bf16(af[m], bf[n], acc[m][n], 0, 0, 0);

    asm volatile("" ::: "memory");     // pin LDS reads before the reuse barrier
    __builtin_amdgcn_s_barrier();      // all waves done reading buffer `buf`
    if (t + 3 < nt) {                  // refill buffer `buf` with tile t+3
      const int kk = (t + 3) << 5;
      char* ab = (char*)As + buf * 8192 + woff;
      char* bb = (char*)Bs + buf * 8192 + woff;
      gload_lds16(A + a0 + kk, ab);
      gload_lds16(A + a1 + kk, ab + 1024);
      gload_lds16(BT + b0 + kk, bb);
      gload_lds16(BT + b1 + kk, bb + 1024);
    }
  }

  float bs[4];
#pragma unroll
  for (int n = 0; n < 4; n++) bs[n] = bias[n0 + wc + n * 16 + lr];
#pragma unroll
  for (int m = 0; m < 4; m++) {
#pragma unroll
    for (int r4 = 0; r4 < 4; r4++) {
      int row = m0 + wr + m * 16 + lg * 4 + r4;
      if (row >= M) continue;
      size_t rb = (size_t)row * N;
#pragma unroll
      for (int n = 0; n < 4; n++) {
        int col = n0 + wc + n * 16 + lr;
        float c = acc[m][n][r4] + bs[n];
        if (EPI == 0) {
          ((unsigned short*)Cout)[rb + col] = f2bf(c);
        } else if (EPI == 1) {
          ((float*)Cout)[rb + col] = c + aux[rb + col];
        } else if (EPI == 2) {
          c = 0.5f * c * (1.f + erff(c * 0.70710678118f));
          ((unsigned short*)Cout)[rb + col] = f2bf(c);
        } else {
          ((float*)Cout)[rb + col] = c + aux[rb + col];   // f32 final output
        }
      }
    }
  }
}

// ---------------- flash attention: qkv bf16 [M,2304] -> attn bf16 [M,768] ----------------
__global__ __launch_bounds__(256) void attn_kernel(const unsigned short* __restrict__ qkv,
                                                   unsigned short* __restrict__ out) {
  __shared__ unsigned short Pl[4 * 16 * 72];
  __shared__ unsigned short VT[64 * 72];
  const int tid = threadIdx.x;
  const int w = tid >> 6, l = tid & 63;
  const int lr = l & 15, lg = l >> 4;
  const int bh = blockIdx.x / 10, qt = blockIdx.x % 10;
  const int b = bh / NHEAD, h = bh % NHEAD;
  const size_t base = (size_t)b * 577 * 2304 + (size_t)h * 64;
  int qr = qt * 64 + w * 16 + lr; int qrc = qr > 576 ? 576 : qr;
  const unsigned short* qp = qkv + base + (size_t)qrc * 2304;
  const s16x8 qf0 = *(const s16x8*)(qp + lg * 8);
  const s16x8 qf1 = *(const s16x8*)(qp + 32 + lg * 8);
  f32x4 oacc[4];
#pragma unroll
  for (int d = 0; d < 4; d++)
#pragma unroll
    for (int r = 0; r < 4; r++) oacc[d][r] = 0.f;
  float mrun = -3e38f, lrun = 0.f;
  unsigned short* Pw = Pl + w * 16 * 72;

  for (int kt = 0; kt < 10; kt++) {
    __syncthreads();
#pragma unroll
    for (int c = 0; c < 2; c++) {
      int cid = c * 256 + tid;
      int kc = cid >> 3, d0 = (cid & 7) * 8;
      int vr = kt * 64 + kc; if (vr > 576) vr = 576;
      s16x8 vv = *(const s16x8*)(qkv + base + 1536 + (size_t)vr * 2304 + d0);
#pragma unroll
      for (int j = 0; j < 8; j++)
        VT[(d0 + j) * 72 + kc] = (unsigned short)vv[j];
    }
    float sv[16];
#pragma unroll
    for (int sub = 0; sub < 4; sub++) {
      int kc = kt * 64 + sub * 16 + lr; if (kc > 576) kc = 576;
      const unsigned short* kp = qkv + base + 768 + (size_t)kc * 2304;
      s16x8 kf0 = *(const s16x8*)(kp + lg * 8);
      s16x8 kf1 = *(const s16x8*)(kp + 32 + lg * 8);
      f32x4 st;
#pragma unroll
      for (int r = 0; r < 4; r++) st[r] = 0.f;
      st = __builtin_amdgcn_mfma_f32_16x16x32_bf16(kf0, qf0, st, 0, 0, 0);
      st = __builtin_amdgcn_mfma_f32_16x16x32_bf16(kf1, qf1, st, 0, 0, 0);
#pragma unroll
      for (int r = 0; r < 4; r++) {
        int kcg = kt * 64 + sub * 16 + lg * 4 + r;
        sv[sub * 4 + r] = (kcg <= 576) ? st[r] * 0.125f : -3e38f;
      }
    }
    float tm = sv[0];
#pragma unroll
    for (int i = 1; i < 16; i++) tm = fmaxf(tm, sv[i]);
    tm = fmaxf(tm, __shfl_xor(tm, 16));
    tm = fmaxf(tm, __shfl_xor(tm, 32));
    float mnew = fmaxf(mrun, tm);
    float fac = __expf(mrun - mnew);
    mrun = mnew;
    float ts = 0.f;
    unsigned short pb[16];
#pragma unroll
    for (int i = 0; i < 16; i++) {
      float p = __expf(sv[i] - mnew);
      ts += p;
      pb[i] = f2bf(p);
    }
    ts += __shfl_xor(ts, 16);
    ts += __shfl_xor(ts, 32);
    lrun = lrun * fac + ts;
#pragma unroll
    for (int sub = 0; sub < 4; sub++) {
      uint2 u;
      u.x = (unsigned)pb[sub * 4 + 0] | ((unsigned)pb[sub * 4 + 1] << 16);
      u.y = (unsigned)pb[sub * 4 + 2] | ((unsigned)pb[sub * 4 + 3] << 16);
      *(uint2*)(Pw + lr * 72 + sub * 16 + lg * 4) = u;
    }
    float fr[4];
#pragma unroll
    for (int r = 0; r < 4; r++) fr[r] = __shfl(fac, lg * 4 + r);
#pragma unroll
    for (int d = 0; d < 4; d++)
#pragma unroll
      for (int r = 0; r < 4; r++) oacc[d][r] *= fr[r];
    __syncthreads();
#pragma unroll
    for (int hf = 0; hf < 2; hf++) {
      s16x8 pf = *(const s16x8*)(Pw + lr * 72 + hf * 32 + lg * 8);
#pragma unroll
      for (int d = 0; d < 4; d++) {
        s16x8 vf = *(const s16x8*)(VT + (d * 16 + lr) * 72 + hf * 32 + lg * 8);
        oacc[d] = __builtin_amdgcn_mfma_f32_16x16x32_bf16(pf, vf, oacc[d], 0, 0, 0);
      }
    }
  }
#pragma unroll
  for (int r = 0; r < 4; r++) {
    int qg = qt * 64 + w * 16 + lg * 4 + r;
    if (qg > 576) continue;
    float inv = 1.f / __shfl(lrun, lg * 4 + r);
#pragma unroll
    for (int d = 0; d < 4; d++)
      out[(size_t)(b * 577 + qg) * 768 + h * 64 + d * 16 + lr] = f2bf(oacc[d][r] * inv);
  }
}

extern "C" void kernel_launch(void* const* d_in, const int* in_sizes, int n_in,
                              void* d_out, int out_size, void* d_ws, size_t ws_size,
                              hipStream_t stream) {
  const float* x      = (const float*)d_in[0];
  const float* w_qkv  = (const float*)d_in[1];
  const float* b_qkv  = (const float*)d_in[2];
  const float* w_proj = (const float*)d_in[3];
  const float* b_proj = (const float*)d_in[4];
  const float* g1  = (const float*)d_in[5];
  const float* be1 = (const float*)d_in[6];
  const float* g2  = (const float*)d_in[7];
  const float* be2 = (const float*)d_in[8];
  const float* g3  = (const float*)d_in[9];
  const float* be3 = (const float*)d_in[10];
  const float* w1  = (const float*)d_in[11];
  const float* bm1 = (const float*)d_in[12];
  const float* w2  = (const float*)d_in[13];
  const float* bm2 = (const float*)d_in[14];

  // workspace layout (bytes), total ~212.7 MB (see round-2 comment)
  char* ws = (char*)d_ws;
  unsigned short* wqkvT  = (unsigned short*)(ws + 0);
  unsigned short* wprojT = (unsigned short*)(ws + 3538944);
  unsigned short* w1T    = (unsigned short*)(ws + 4718592);
  unsigned short* w2T    = (unsigned short*)(ws + 9437184);
  unsigned short* hbuf   = (unsigned short*)(ws + 14155776);
  unsigned short* qkv    = (unsigned short*)(ws + 42516480);
  unsigned short* hid    = qkv;
  unsigned short* attnb  = hbuf;   // alias: h1 dead after QKV GEMM
  float*          res1   = (float*)(ws + 155959296);

  dim3 b32(32, 8);
  wtrans<<<dim3(2304 / 32, 768 / 32),  b32, 0, stream>>>(w_qkv,  wqkvT,  768, 2304);
  wtrans<<<dim3(768 / 32, 768 / 32),   b32, 0, stream>>>(w_proj, wprojT, 768, 768);
  wtrans<<<dim3(3072 / 32, 768 / 32),  b32, 0, stream>>>(w1,     w1T,    768, 3072);
  wtrans<<<dim3(768 / 32, 3072 / 32),  b32, 0, stream>>>(w2,     w2T,    3072, 768);

  ln1_kernel<<<4616, 256, 0, stream>>>(x, g1, be1, hbuf);
  gemm_nt<0><<<dim3(18, 145), 256, 0, stream>>>(hbuf, wqkvT, b_qkv, nullptr, qkv, M_ROWS, 2304, 768);
  attn_kernel<<<3840, 256, 0, stream>>>(qkv, attnb);
  gemm_nt<1><<<dim3(6, 145), 256, 0, stream>>>(attnb, wprojT, b_proj, x, res1, M_ROWS, 768, 768);
  ln2_kernel<<<4616, 256, 0, stream>>>(res1, g2, be2, g3, be3, hbuf);
  gemm_nt<2><<<dim3(24, 145), 256, 0, stream>>>(hbuf, w1T, bm1, nullptr, hid, M_ROWS, 3072, 768);
  gemm_nt<3><<<dim3(6, 145), 256, 0, stream>>>(hid, w2T, bm2, res1, (float*)d_out, M_ROWS, 768, 3072);
}